// Round 1
// baseline (725.863 us; speedup 1.0000x reference)
//
#include <hip/hip_runtime.h>
#include <stdint.h>

// Keep hipcc from contracting mul+add into FMA behind our back: the JAX
// reference (eager mode) has no cross-op FMA, and where XLA *does* fuse we
// write fmaf() explicitly.
#pragma clang fp contract(off)

#define PD   162
#define PD2  (162*162)
#define PD3  (162*162*162)
#define NPAD (2*PD3)          // 8,503,056 padded voxels
#define OD   160
#define OD2  (160*160)
#define OD3  (160*160*160)
#define NOUT (2*OD3)          // 8,192,000 output voxels
#define SF   81
#define SF2  (81*81)
#define SF3  (81*81*81)
#define NSF  (2*SF3)          // 1,062,882 voxels per subfield pass

// ---------------- threefry2x32, JAX partitionable scheme --------------------
// key = (0, 42) from jax.random.key(42); per element i (flat index over the
// padded shape): counts = (hi=0, lo=i); bits = out0 ^ out1.
__device__ __forceinline__ uint32_t rotl32(uint32_t x, uint32_t r) {
  return (x << r) | (x >> (32u - r));
}

__device__ __forceinline__ uint32_t threefry_bits(uint32_t idx) {
  const uint32_t ks0 = 0u, ks1 = 42u, ks2 = 0x1BD11BDAu ^ 0u ^ 42u;
  uint32_t x0 = 0u + ks0;
  uint32_t x1 = idx + ks1;
#define TFR(r) { x0 += x1; x1 = rotl32(x1, (r)); x1 ^= x0; }
  TFR(13u) TFR(15u) TFR(26u) TFR(6u)
  x0 += ks1; x1 += ks2 + 1u;
  TFR(17u) TFR(29u) TFR(16u) TFR(24u)
  x0 += ks2; x1 += ks0 + 2u;
  TFR(13u) TFR(15u) TFR(26u) TFR(6u)
  x0 += ks0; x1 += ks1 + 3u;
  TFR(17u) TFR(29u) TFR(16u) TFR(24u)
  x0 += ks1; x1 += ks2 + 4u;
  TFR(13u) TFR(15u) TFR(26u) TFR(6u)
  x0 += ks2; x1 += ks0 + 5u;
#undef TFR
  return x0 ^ x1;
}

// ------------- XLA-CPU (Cephes) float32 log replication ---------------------
__device__ __forceinline__ float xla_logf(float xin) {
  // assumes xin positive, normal (true for all our inputs)
  uint32_t bits = __float_as_uint(xin);
  float e = (float)((int)(bits >> 23) - 126);
  float x = __uint_as_float((bits & 0x007fffffu) | 0x3f000000u); // [0.5,1)
  const float SQRTHF = 0.707106781186547524f;
  bool lt = (x < SQRTHF);
  float tmp = lt ? x : 0.0f;
  e = e - (lt ? 1.0f : 0.0f);
  x = x - 1.0f;
  x = x + tmp;
  float z = x * x;
  float y = 7.0376836292e-2f;
  y = fmaf(y, x, -1.1514610310e-1f);
  y = fmaf(y, x,  1.1676998740e-1f);
  y = fmaf(y, x, -1.2420140846e-1f);
  y = fmaf(y, x,  1.4249322787e-1f);
  y = fmaf(y, x, -1.6668057665e-1f);
  y = fmaf(y, x,  2.0000714765e-1f);
  y = fmaf(y, x, -2.4999993993e-1f);
  y = fmaf(y, x,  3.3333331174e-1f);
  y = y * x;
  y = y * z;
  y = fmaf(e, -2.12194440e-4f, y);   // y += e*q1
  y = fmaf(-0.5f, z, y);             // y -= 0.5*z (contracted)
  x = x + y;
  x = fmaf(e, 0.693359375f, x);      // x += e*q2
  return x;
}

// XLA ElementalIrEmitter::EmitLog1p
__device__ __forceinline__ float xla_log1pf(float x) {
  float for_large = xla_logf(x + 1.0f);
  float for_small = fmaf(-0.5f, x, 1.0f) * x;
  return (fabsf(x) < 1e-4f) ? for_small : for_large;
}

// ---------------------------- kernels ---------------------------------------
__global__ __launch_bounds__(256) void k_binarize(const float* __restrict__ in,
                                                  uint8_t* __restrict__ img) {
  uint32_t i = blockIdx.x * 256u + threadIdx.x;
  if (i >= (uint32_t)NPAD) return;
  uint32_t n = i / (uint32_t)PD3;
  uint32_t r = i - n * (uint32_t)PD3;
  uint32_t z = r / (uint32_t)PD2; r -= z * (uint32_t)PD2;
  uint32_t y = r / (uint32_t)PD;
  uint32_t x = r - y * (uint32_t)PD;
  float v = 0.0f;
  if ((z - 1u) < (uint32_t)OD && (y - 1u) < (uint32_t)OD && (x - 1u) < (uint32_t)OD)
    v = in[((n * OD + (z - 1u)) * OD + (y - 1u)) * OD + (x - 1u)];
  uint32_t bits = threefry_bits(i);
  // jax.random.uniform: floats in [0,1) from high mantissa bits; scale==1.0f
  float f = __uint_as_float((bits >> 9) | 0x3f800000u) - 1.0f;
  float uu = f + 1e-8f;
  uu = fmaxf(1e-8f, uu);
  float la = xla_logf((v + 1e-8f) / ((1.0f - v) + 1e-8f));
  float noise = xla_logf(uu) - xla_log1pf(-uu);
  float zs = la + noise * 0.33f;   // BETA=0.33, TAU=1.0 (exact /1.0 elided)
  // logistic = 0.5 + 0.5*tanh(0.5 z); > 0.5 iff z > 2^-23 (ties round to 0.5)
  img[i] = (zs > 1.1920928955078125e-7f) ? (uint8_t)1 : (uint8_t)0;
}

__global__ __launch_bounds__(256) void k_endpoint(const uint8_t* __restrict__ img,
                                                  uint8_t* __restrict__ isend) {
  int i = blockIdx.x * 256 + threadIdx.x;
  if (i >= NPAD) return;
  if (img[i] == 0) return;        // only needed where img==1 (ring is 0 -> interior only)
  int cnt = 0;
#pragma unroll
  for (int dz = -1; dz <= 1; ++dz)
#pragma unroll
    for (int dy = -1; dy <= 1; ++dy) {
      const uint8_t* p = img + (i + dz * PD2 + dy * PD - 1);
      cnt += (int)p[0] + (int)p[1] + (int)p[2];
    }
  int c26 = cnt - 1;              // center is 1
  isend[i] = (c26 <= 1) ? (uint8_t)1 : (uint8_t)0;
}

#define BITI(dz,dy,dx) ((((dz)+1)*9) + (((dy)+1)*3) + ((dx)+1))
#define BB(dz,dy,dx) (1u << BITI(dz,dy,dx))
#define OCT6(sz,sy,sx) (BB(sz,0,0)|BB(0,sy,0)|BB(0,0,sx)|BB(sz,sy,0)|BB(sz,0,sx)|BB(0,sy,sx))

__global__ __launch_bounds__(256) void k_subfield(uint8_t* __restrict__ img,
                                                  const uint8_t* __restrict__ isend,
                                                  int o2, int o3, int o4) {
  uint32_t t = blockIdx.x * 256u + threadIdx.x;
  if (t >= (uint32_t)NSF) return;
  uint32_t n  = t / (uint32_t)SF3;
  uint32_t r  = t - n * (uint32_t)SF3;
  uint32_t i2 = r / (uint32_t)SF2; r -= i2 * (uint32_t)SF2;
  uint32_t i3 = r / (uint32_t)SF;
  uint32_t i4 = r - i3 * (uint32_t)SF;
  int z = o2 + 2 * (int)i2;
  int y = o3 + 2 * (int)i3;
  int x = o4 + 2 * (int)i4;
  int c = (int)n * PD3 + z * PD2 + y * PD + x;
  if (img[c] == 0) return;        // nothing to delete (also covers boundary ring)
  if (isend[c] != 0) return;      // endpoint: never deleted
  // gather 27-bit neighborhood mask (center guaranteed interior)
  uint32_t m = 0; int b = 0;
#pragma unroll
  for (int dz = -1; dz <= 1; ++dz)
#pragma unroll
    for (int dy = -1; dy <= 1; ++dy) {
      const uint8_t* p = img + (c + dz * PD2 + dy * PD - 1);
      m |= ((uint32_t)p[0]) << b;
      m |= ((uint32_t)p[1]) << (b + 1);
      m |= ((uint32_t)p[2]) << (b + 2);
      b += 3;
    }
  const uint32_t FACE6 = BB(-1,0,0)|BB(1,0,0)|BB(0,-1,0)|BB(0,1,0)|BB(0,0,-1)|BB(0,0,1);
  const uint32_t ALL27 = (1u << 27) - 1u;
  const uint32_t N26M  = ALL27 & ~BB(0,0,0);
  const uint32_t CORN  = BB(-1,-1,-1)|BB(-1,-1,1)|BB(-1,1,-1)|BB(-1,1,1)
                       | BB(1,-1,-1)|BB(1,-1,1)|BB(1,1,-1)|BB(1,1,1);
  const uint32_t N18M  = N26M & ~CORN;
  int C6  = __popc(m & FACE6);
  int C26 = __popc(m & N26M);
  int C18 = __popc(m & N18M);
  // B0: no corner q with corner-bit set and all 6 octant face/edge cells clear
  const uint32_t cb[8] = { BB(-1,-1,-1), BB(-1,-1,1), BB(-1,1,-1), BB(-1,1,1),
                           BB(1,-1,-1),  BB(1,-1,1),  BB(1,1,-1),  BB(1,1,1) };
  const uint32_t co[8] = { OCT6(-1,-1,-1), OCT6(-1,-1,1), OCT6(-1,1,-1), OCT6(-1,1,1),
                           OCT6(1,-1,-1),  OCT6(1,-1,1),  OCT6(1,1,-1),  OCT6(1,1,1) };
  bool B0 = true;
#pragma unroll
  for (int q = 0; q < 8; ++q)
    if ((m & cb[q]) != 0u && (m & co[q]) == 0u) B0 = false;
  // A0: no direction d with face cell clear and full 4-cell in-plane ring set
  const uint32_t fb[6] = { BB(-1,0,0), BB(1,0,0), BB(0,-1,0), BB(0,1,0), BB(0,0,-1), BB(0,0,1) };
  const uint32_t rg[6] = {
    BB(-1,-1,0)|BB(-1,1,0)|BB(-1,0,-1)|BB(-1,0,1),
    BB(1,-1,0)|BB(1,1,0)|BB(1,0,-1)|BB(1,0,1),
    BB(-1,-1,0)|BB(1,-1,0)|BB(0,-1,-1)|BB(0,-1,1),
    BB(-1,1,0)|BB(1,1,0)|BB(0,1,-1)|BB(0,1,1),
    BB(-1,0,-1)|BB(1,0,-1)|BB(0,-1,-1)|BB(0,1,-1),
    BB(-1,0,1)|BB(1,0,1)|BB(0,-1,1)|BB(0,1,1)
  };
  bool A0 = true;
#pragma unroll
  for (int q = 0; q < 6; ++q)
    if ((m & fb[q]) == 0u && (m & rg[q]) == rg[q]) A0 = false;

  bool simple = (C6 == 5) || (C26 == 1) || ((C18 == 1) && B0) ||
                ((C6 <= 4) && A0 && B0);
  if (simple) img[c] = 0;
}

__global__ __launch_bounds__(256) void k_output(const uint8_t* __restrict__ img,
                                                float* __restrict__ out) {
  uint32_t i = blockIdx.x * 256u + threadIdx.x;
  if (i >= (uint32_t)NOUT) return;
  uint32_t n = i / (uint32_t)OD3;
  uint32_t r = i - n * (uint32_t)OD3;
  uint32_t z = r / (uint32_t)OD2; r -= z * (uint32_t)OD2;
  uint32_t y = r / (uint32_t)OD;
  uint32_t x = r - y * (uint32_t)OD;
  out[i] = (float)img[(int)n * PD3 + (int)(z + 1u) * PD2 + (int)(y + 1u) * PD + (int)(x + 1u)];
}

// ---------------------------- launcher --------------------------------------
extern "C" void kernel_launch(void* const* d_in, const int* in_sizes, int n_in,
                              void* d_out, int out_size, void* d_ws, size_t ws_size,
                              hipStream_t stream) {
  const float* in = (const float*)d_in[0];
  float* out = (float*)d_out;
  uint8_t* img = (uint8_t*)d_ws;          // NPAD bytes
  uint8_t* isend = img + NPAD;            // NPAD bytes  (total ~17 MB)

  const int offs[8][3] = { {0,0,0},{1,0,0},{0,1,0},{1,1,0},
                           {0,0,1},{1,0,1},{0,1,1},{1,1,1} };

  dim3 blk(256);
  k_binarize<<<dim3((NPAD + 255) / 256), blk, 0, stream>>>(in, img);
  for (int it = 0; it < 5; ++it) {
    k_endpoint<<<dim3((NPAD + 255) / 256), blk, 0, stream>>>(img, isend);
    for (int s = 0; s < 8; ++s) {
      k_subfield<<<dim3((NSF + 255) / 256), blk, 0, stream>>>(
          img, isend, offs[s][0], offs[s][1], offs[s][2]);
    }
  }
  k_output<<<dim3((NOUT + 255) / 256), blk, 0, stream>>>(img, out);
}

// Round 2
// 315.852 us; speedup vs baseline: 2.2981x; 2.2981x over previous
//
#include <hip/hip_runtime.h>
#include <stdint.h>

// No implicit FMA contraction: the JAX eager reference has none across ops;
// where XLA fuses we write fmaf() explicitly.
#pragma clang fp contract(off)

#define PDIM 162
#define ROWS (2*PDIM*PDIM)      // 52488 rows (n,z,y)
#define WPR  3                  // 64-bit words per row (192 bits >= 162)
#define NW   (ROWS*WPR)         // 157464 words, 1.26 MB per bitboard
#define OD   160
#define OD2  (160*160)
#define OD3  (160*160*160)
#define NOUT (2*OD3)

// ---------------- threefry2x32, JAX partitionable scheme --------------------
__device__ __forceinline__ uint32_t rotl32(uint32_t x, uint32_t r) {
  return (x << r) | (x >> (32u - r));
}

__device__ __forceinline__ uint32_t threefry_bits(uint32_t idx) {
  const uint32_t ks0 = 0u, ks1 = 42u, ks2 = 0x1BD11BDAu ^ 0u ^ 42u;
  uint32_t x0 = 0u + ks0;
  uint32_t x1 = idx + ks1;
#define TFR(r) { x0 += x1; x1 = rotl32(x1, (r)); x1 ^= x0; }
  TFR(13u) TFR(15u) TFR(26u) TFR(6u)
  x0 += ks1; x1 += ks2 + 1u;
  TFR(17u) TFR(29u) TFR(16u) TFR(24u)
  x0 += ks2; x1 += ks0 + 2u;
  TFR(13u) TFR(15u) TFR(26u) TFR(6u)
  x0 += ks0; x1 += ks1 + 3u;
  TFR(17u) TFR(29u) TFR(16u) TFR(24u)
  x0 += ks1; x1 += ks2 + 4u;
  TFR(13u) TFR(15u) TFR(26u) TFR(6u)
  x0 += ks2; x1 += ks0 + 5u;
#undef TFR
  return x0 ^ x1;
}

// ------------- XLA-CPU (Cephes) float32 log replication ---------------------
__device__ __forceinline__ float xla_logf(float xin) {
  uint32_t bits = __float_as_uint(xin);
  float e = (float)((int)(bits >> 23) - 126);
  float x = __uint_as_float((bits & 0x007fffffu) | 0x3f000000u);
  const float SQRTHF = 0.707106781186547524f;
  bool lt = (x < SQRTHF);
  float tmp = lt ? x : 0.0f;
  e = e - (lt ? 1.0f : 0.0f);
  x = x - 1.0f;
  x = x + tmp;
  float z = x * x;
  float y = 7.0376836292e-2f;
  y = fmaf(y, x, -1.1514610310e-1f);
  y = fmaf(y, x,  1.1676998740e-1f);
  y = fmaf(y, x, -1.2420140846e-1f);
  y = fmaf(y, x,  1.4249322787e-1f);
  y = fmaf(y, x, -1.6668057665e-1f);
  y = fmaf(y, x,  2.0000714765e-1f);
  y = fmaf(y, x, -2.4999993993e-1f);
  y = fmaf(y, x,  3.3333331174e-1f);
  y = y * x;
  y = y * z;
  y = fmaf(e, -2.12194440e-4f, y);
  y = fmaf(-0.5f, z, y);
  x = x + y;
  x = fmaf(e, 0.693359375f, x);
  return x;
}

__device__ __forceinline__ float xla_log1pf(float x) {
  float for_large = xla_logf(x + 1.0f);
  float for_small = fmaf(-0.5f, x, 1.0f) * x;
  return (fabsf(x) < 1e-4f) ? for_small : for_large;
}

// ---------------------------- kernels ---------------------------------------
// One wave (64 lanes) computes 64 voxel decisions and packs them via ballot.
__global__ __launch_bounds__(256) void k_binarize(const float* __restrict__ in,
                                                  uint64_t* __restrict__ bits) {
  uint32_t t = blockIdx.x * 256u + threadIdx.x;
  uint32_t w = t >> 6, lane = t & 63u;
  if (w >= (uint32_t)NW) return;          // wave-uniform (w shared by the wave)
  uint32_t row = w / 3u, wx = w - row * 3u;
  uint32_t n  = row / (uint32_t)(PDIM * PDIM);
  uint32_t rr = row - n * (uint32_t)(PDIM * PDIM);
  uint32_t z  = rr / (uint32_t)PDIM;
  uint32_t y  = rr - z * (uint32_t)PDIM;
  uint32_t x  = wx * 64u + lane;
  bool pred = false;
  if (x < (uint32_t)PDIM) {
    float v = 0.0f;
    if ((z - 1u) < 160u && (y - 1u) < 160u && (x - 1u) < 160u)
      v = in[((n * 160u + (z - 1u)) * 160u + (y - 1u)) * 160u + (x - 1u)];
    uint32_t i = row * 162u + x;          // flat padded index for RNG
    uint32_t b = threefry_bits(i);
    float f  = __uint_as_float((b >> 9) | 0x3f800000u) - 1.0f;
    float uu = fmaxf(1e-8f, f + 1e-8f);
    float la = xla_logf((v + 1e-8f) / ((1.0f - v) + 1e-8f));
    float noise = xla_logf(uu) - xla_log1pf(-uu);
    float zs = la + noise * 0.33f;
    pred = (zs > 1.1920928955078125e-7f); // logistic>0.5 iff z>2^-23
  }
  uint64_t m = __ballot(pred);
  if (lane == 0) bits[w] = m;
}

// ge2[w] bit p = (26-neighborhood count >= 2)  [i.e. NOT endpoint]
__global__ __launch_bounds__(256) void k_endpoint(const uint64_t* __restrict__ bits,
                                                  uint64_t* __restrict__ ge2) {
  uint32_t t = blockIdx.x * 256u + threadIdx.x;
  if (t >= 2u * 160u * 160u * 3u) return;
  uint32_t r160 = t / 3u, wx = t - r160 * 3u;
  uint32_t n  = r160 / (160u * 160u);
  uint32_t rr = r160 - n * (160u * 160u);
  uint32_t z  = rr / 160u + 1u;
  uint32_t y  = rr - (rr / 160u) * 160u + 1u;
  int row = (int)((n * 162u + z) * 162u + y);
  uint64_t s = 0, c = 0;
#define ACC(bb) { uint64_t _b = (bb); c |= s & _b; s |= _b; }
#pragma unroll
  for (int dz = -1; dz <= 1; ++dz)
#pragma unroll
    for (int dy = -1; dy <= 1; ++dy) {
      uint32_t idx = (uint32_t)(row + dz * 162 + dy) * 3u + wx;
      uint64_t b = bits[idx];
      uint64_t a = (wx > 0u) ? bits[idx - 1u] : 0ull;
      uint64_t d = (wx < 2u) ? bits[idx + 1u] : 0ull;
      ACC((b << 1) | (a >> 63));          // x-1 neighbor
      ACC((b >> 1) | (d << 63));          // x+1 neighbor
      if (dz != 0 || dy != 0) ACC(b);     // same-x neighbor (skip center)
    }
#undef ACC
  ge2[row * 3 + (int)wx] = c;
}

#define NB(dz,dy,dx) ((dx)==-1 ? Lb[(dz)+1][(dy)+1] : ((dx)==1 ? Rb[(dz)+1][(dy)+1] : V[(dz)+1][(dy)+1]))

__global__ __launch_bounds__(256) void k_subfield(uint64_t* __restrict__ bits,
                                                  const uint64_t* __restrict__ ge2,
                                                  int zbase, int ybase, uint64_t xmask) {
  uint32_t t = blockIdx.x * 256u + threadIdx.x;
  if (t >= 2u * 80u * 80u * 3u) return;
  uint32_t ri = t / 3u, wx = t - ri * 3u;
  uint32_t n  = ri / (80u * 80u);
  uint32_t rr = ri - n * (80u * 80u);
  uint32_t zi = rr / 80u, yi = rr - zi * 80u;
  uint32_t z = (uint32_t)zbase + 2u * zi;  // interior subfield rows only
  uint32_t y = (uint32_t)ybase + 2u * yi;
  int row = (int)((n * 162u + z) * 162u + y);
  uint32_t w = (uint32_t)row * 3u + wx;
  uint64_t center = bits[w];
  uint64_t active = center & xmask & ge2[w];   // img==1, subfield, not-endpoint
  if (active == 0ull) return;

  uint64_t V[3][3], Lb[3][3], Rb[3][3];
#pragma unroll
  for (int dz = -1; dz <= 1; ++dz)
#pragma unroll
    for (int dy = -1; dy <= 1; ++dy) {
      uint32_t idx = (uint32_t)(row + dz * 162 + dy) * 3u + wx;
      uint64_t b = bits[idx];
      uint64_t a = (wx > 0u) ? bits[idx - 1u] : 0ull;
      uint64_t d = (wx < 2u) ? bits[idx + 1u] : 0ull;
      V [dz+1][dy+1] = b;
      Lb[dz+1][dy+1] = (b << 1) | (a >> 63);
      Rb[dz+1][dy+1] = (b >> 1) | (d << 63);
    }

  // --- C6 exact 3-bit counter over the 6 faces ---
  uint64_t on = 0, tw = 0, fo = 0;
#define C6ADD(b) { uint64_t _u = on & (b); on ^= (b); uint64_t _v = tw & _u; tw ^= _u; fo |= _v; }
  C6ADD(NB(-1,0,0)) C6ADD(NB(1,0,0)) C6ADD(NB(0,-1,0))
  C6ADD(NB(0,1,0))  C6ADD(NB(0,0,-1)) C6ADD(NB(0,0,1))
#undef C6ADD
  uint64_t c6eq5 = fo & on & ~tw;          // count == 5 (101b)
  uint64_t c6le4 = ~(fo & (on | tw));      // count <= 4

  // --- carry-save OR/ge2 over 18 then 26 neighbors ---
  uint64_t s = 0, c2 = 0;
#define CS(b) { uint64_t _b = (b); c2 |= s & _b; s |= _b; }
  CS(NB(-1,0,0)) CS(NB(1,0,0)) CS(NB(0,-1,0)) CS(NB(0,1,0)) CS(NB(0,0,-1)) CS(NB(0,0,1))
  CS(NB(-1,-1,0)) CS(NB(-1,1,0)) CS(NB(-1,0,-1)) CS(NB(-1,0,1))
  CS(NB(1,-1,0))  CS(NB(1,1,0))  CS(NB(1,0,-1))  CS(NB(1,0,1))
  CS(NB(0,-1,-1)) CS(NB(0,-1,1)) CS(NB(0,1,-1))  CS(NB(0,1,1))
  uint64_t e18 = s & ~c2;                  // C18 == 1
  CS(NB(-1,-1,-1)) CS(NB(-1,-1,1)) CS(NB(-1,1,-1)) CS(NB(-1,1,1))
  CS(NB(1,-1,-1))  CS(NB(1,-1,1))  CS(NB(1,1,-1))  CS(NB(1,1,1))
  uint64_t e26 = s & ~c2;                  // C26 == 1
#undef CS

  // --- B pattern: corner set with its 6 octant face/edge cells all clear ---
  uint64_t badB = 0;
#pragma unroll
  for (int sz = -1; sz <= 1; sz += 2)
#pragma unroll
    for (int sy = -1; sy <= 1; sy += 2)
#pragma unroll
      for (int sx = -1; sx <= 1; sx += 2) {
        uint64_t oct = NB(sz,0,0) | NB(0,sy,0) | NB(0,0,sx)
                     | NB(sz,sy,0) | NB(sz,0,sx) | NB(0,sy,sx);
        badB |= NB(sz,sy,sx) & ~oct;
      }
  uint64_t b0ok = ~badB;

  // --- A pattern: face clear with its full 4-cell in-plane ring set ---
  uint64_t badA = 0;
  badA |= ~NB(-1,0,0) & NB(-1,-1,0) & NB(-1,1,0) & NB(-1,0,-1) & NB(-1,0,1);
  badA |= ~NB( 1,0,0) & NB( 1,-1,0) & NB( 1,1,0) & NB( 1,0,-1) & NB( 1,0,1);
  badA |= ~NB(0,-1,0) & NB(-1,-1,0) & NB(1,-1,0) & NB(0,-1,-1) & NB(0,-1,1);
  badA |= ~NB(0, 1,0) & NB(-1, 1,0) & NB(1, 1,0) & NB(0, 1,-1) & NB(0, 1,1);
  badA |= ~NB(0,0,-1) & NB(-1,0,-1) & NB(1,0,-1) & NB(0,-1,-1) & NB(0,1,-1);
  badA |= ~NB(0,0, 1) & NB(-1,0, 1) & NB(1,0, 1) & NB(0,-1, 1) & NB(0,1, 1);
  uint64_t a0ok = ~badA;

  uint64_t simple = c6eq5 | e26 | (e18 & b0ok) | (c6le4 & a0ok & b0ok);
  uint64_t del = simple & active;
  if (del) bits[w] = center & ~del;
}

__global__ __launch_bounds__(256) void k_output(const uint64_t* __restrict__ bits,
                                                float4* __restrict__ out) {
  uint32_t t = blockIdx.x * 256u + threadIdx.x;
  if (t >= (uint32_t)(NOUT / 4)) return;
  uint32_t i = t * 4u;
  uint32_t n = i / (uint32_t)OD3;
  uint32_t r = i - n * (uint32_t)OD3;
  uint32_t z = r / (uint32_t)OD2; r -= z * (uint32_t)OD2;
  uint32_t y = r / (uint32_t)OD;
  uint32_t x = r - y * (uint32_t)OD;
  uint32_t row = (n * 162u + z + 1u) * 162u + (y + 1u);
  uint32_t bi = x + 1u;
  uint32_t wx = bi >> 6, sft = bi & 63u;
  uint64_t v = bits[row * 3u + wx] >> sft;
  if (sft > 60u) v |= bits[row * 3u + wx + 1u] << (64u - sft);
  out[t] = make_float4((float)(v & 1u), (float)((v >> 1) & 1u),
                       (float)((v >> 2) & 1u), (float)((v >> 3) & 1u));
}

// ---------------------------- launcher --------------------------------------
extern "C" void kernel_launch(void* const* d_in, const int* in_sizes, int n_in,
                              void* d_out, int out_size, void* d_ws, size_t ws_size,
                              hipStream_t stream) {
  const float* in = (const float*)d_in[0];
  float4* out = (float4*)d_out;
  uint64_t* bits = (uint64_t*)d_ws;        // NW words (1.26 MB)
  uint64_t* ge2  = bits + NW;              // NW words

  const int offs[8][3] = { {0,0,0},{1,0,0},{0,1,0},{1,1,0},
                           {0,0,1},{1,0,1},{0,1,1},{1,1,1} };

  dim3 blk(256);
  k_binarize<<<dim3((NW * 64 + 255) / 256), blk, 0, stream>>>(in, bits);
  const uint32_t NE = 2u * 160u * 160u * 3u;
  const uint32_t NS = 2u * 80u * 80u * 3u;
  for (int it = 0; it < 5; ++it) {
    k_endpoint<<<dim3((NE + 255) / 256), blk, 0, stream>>>(bits, ge2);
    for (int sfi = 0; sfi < 8; ++sfi) {
      int o2 = offs[sfi][0], o3 = offs[sfi][1], o4 = offs[sfi][2];
      int zbase = (o2 == 0) ? 2 : 1;       // interior rows of this parity
      int ybase = (o3 == 0) ? 2 : 1;
      uint64_t xmask = (o4 == 0) ? 0x5555555555555555ull : 0xAAAAAAAAAAAAAAAAull;
      k_subfield<<<dim3((NS + 255) / 256), blk, 0, stream>>>(
          bits, ge2, zbase, ybase, xmask);
    }
  }
  k_output<<<dim3((NOUT / 4 + 255) / 256), blk, 0, stream>>>(bits, out);
}